// Round 13
// baseline (215.620 us; speedup 1.0000x reference)
//
#include <hip/hip_runtime.h>

#define NB_HG 2048   // H*G = 32*64
#define DIM_N 128
#define DIM_D 128
#define DIM_S 256
#define PH 32        // staged rows per phase
#define BSW 128      // staged B width = block's s-window

// Numerics: golden = per-element strictly sequential ascending-d fp32 FMA over
// the SELECTED d's only (masked-out terms exact zeros). Verified bit-exact
// rounds 4-12. Compaction + phase split preserve chain order; X/B pass through
// regs+LDS unmodified (same bits).
// LDS swizzle pos = idx ^ (4*(row&7)) — SQ_LDS_BANK_CONFLICT=0 verified r5-12.
// This round (T14 async-STAGE): phase p+1's global loads are ISSUED before
// COMPUTE(p) into registers (vmcnt in flight across the pure-LDS compute,
// which only uses lgkmcnt), then ds_written after the post-compute barrier.
// Hides the ~200-900cy staging latency that was 41% idle in R12.

__global__ void transpose_proj_kernel(const float* __restrict__ proj,
                                      float* __restrict__ projT)
{
    const int d = blockIdx.x;                      // 128
    const int s = threadIdx.x;                     // 256
    projT[d * DIM_S + s] = proj[s * DIM_D + d];    // coalesced write
}

template<bool TP>
__global__ __launch_bounds__(256)
void qjl_sketch_kernel(const float* __restrict__ data,
                       const float* __restrict__ mask,
                       const float* __restrict__ pmat,   // TP ? projT[d][s] : proj[s][d]
                       int* __restrict__ out)
{
    __shared__ float Xt[PH * DIM_N];               // 16 KB
    __shared__ float Bs[PH * BSW];                 // 16 KB
    __shared__ int   cidx[DIM_D];
    __shared__ int   wcnt[2];

    const int type = blockIdx.x;   // 0: inlier s<128, 1: inlier s>=128, 2: outlier s<128
    const int hg   = blockIdx.y;
    const int tid  = threadIdx.x;

    // ---------- build compacted ascending list of selected d's ----------
    bool sel = false; int pos = 0, w = 0;
    if (tid < 128) {                               // waves 0,1 only (whole waves)
        const float m = mask[hg * DIM_D + tid];    // exactly 0.0f or 1.0f
        sel = (type == 2) ? (m != 0.0f) : (m == 0.0f);
        const unsigned long long bal = __ballot(sel);
        const int lane = tid & 63;
        w = tid >> 6;
        if (lane == 0) wcnt[w] = __popcll(bal);
        pos = __popcll(bal & ((1ull << lane) - 1ull));
    }
    __syncthreads();
    if (sel) cidx[pos + (w ? wcnt[0] : 0)] = tid;  // tid == d, ascending preserved
    __syncthreads();
    const int K = wcnt[0] + wcnt[1];               // uniform across block

    const int tn = tid & 15;                       // 16 n-groups
    const int ts = tid >> 4;                       // 16 s-groups
    const int C0 = 4 * tn;
    const int sl = ts * 8;                         // s_local base
    const int sbase = (type == 1) ? 128 : 0;

    float acc[8][8];                               // [j: s-bit][i: n-slot]
    #pragma unroll
    for (int j = 0; j < 8; ++j)
        #pragma unroll
        for (int i = 0; i < 8; ++i) acc[j][i] = 0.0f;

    // staging thread mapping (constant across phases)
    const int cl_s  = tid & 31;                    // LDS row this thread stages
    const int nh    = tid >> 5;                    // 0..7: 16-wide slice
    const int pcs_s = 4 * (cl_s & 7);
    float* xrow = &Xt[cl_s * DIM_N];
    float* brow = &Bs[cl_s * BSW];

    float4 xr[4], br[4];                           // in-flight staging registers

    // issue global loads for phase rows [base, base+kp) into regs (no LDS)
    auto LOADR = [&](int base, int kp) {
        if (cl_s < kp) {
            const int dg = cidx[base + cl_s];
            const float* Xs = data + (size_t)hg * (DIM_N * DIM_D) + dg;
            #pragma unroll
            for (int g = 0; g < 4; ++g) {
                const int n0 = nh * 16 + g * 4;
                xr[g].x = Xs[(size_t)(n0 + 0) * DIM_D];
                xr[g].y = Xs[(size_t)(n0 + 1) * DIM_D];
                xr[g].z = Xs[(size_t)(n0 + 2) * DIM_D];
                xr[g].w = Xs[(size_t)(n0 + 3) * DIM_D];
            }
            if (TP) {
                const float* Ps = pmat + (size_t)dg * DIM_S + sbase;
                #pragma unroll
                for (int g = 0; g < 4; ++g)
                    br[g] = *reinterpret_cast<const float4*>(Ps + nh * 16 + g * 4);
            } else {
                #pragma unroll
                for (int g = 0; g < 4; ++g) {
                    const int s0l = nh * 16 + g * 4;
                    br[g].x = pmat[(size_t)(sbase + s0l + 0) * DIM_D + dg];
                    br[g].y = pmat[(size_t)(sbase + s0l + 1) * DIM_D + dg];
                    br[g].z = pmat[(size_t)(sbase + s0l + 2) * DIM_D + dg];
                    br[g].w = pmat[(size_t)(sbase + s0l + 3) * DIM_D + dg];
                }
            }
        }
    };
    // drain vmcnt (first reg use) and commit regs to swizzled LDS
    auto WRITER = [&](int kp) {
        if (cl_s < kp) {
            #pragma unroll
            for (int g = 0; g < 4; ++g) {
                const int n0 = nh * 16 + g * 4;
                *reinterpret_cast<float4*>(&xrow[n0 ^ pcs_s]) = xr[g];
                *reinterpret_cast<float4*>(&brow[n0 ^ pcs_s]) = br[g];
            }
        }
    };

    auto COMPUTE = [&](int kp) {
        #pragma unroll 8
        for (int cl = 0; cl < kp; ++cl) {          // ascending selected d
            const int pcs = 4 * (cl & 7);          // compile-time under unroll
            const int pA  = sl ^ pcs;              // holds s_local sl..sl+3
            const float4 bA = *reinterpret_cast<const float4*>(&Bs[cl * BSW + pA]);
            const float4 bB = *reinterpret_cast<const float4*>(&Bs[cl * BSW + (pA ^ 4)]);
            const int P = C0 ^ pcs;
            const float4 q0 = *reinterpret_cast<const float4*>(&Xt[cl * DIM_N + P]);
            const float4 q1 = *reinterpret_cast<const float4*>(&Xt[cl * DIM_N + P + 64]);
            const float bv[8] = {bA.x, bA.y, bA.z, bA.w, bB.x, bB.y, bB.z, bB.w};

            #pragma unroll
            for (int j = 0; j < 8; ++j) {
                acc[j][0] = fmaf(bv[j], q0.x, acc[j][0]);   // serial dep: order fixed
                acc[j][1] = fmaf(bv[j], q0.y, acc[j][1]);
                acc[j][2] = fmaf(bv[j], q0.z, acc[j][2]);
                acc[j][3] = fmaf(bv[j], q0.w, acc[j][3]);
                acc[j][4] = fmaf(bv[j], q1.x, acc[j][4]);
                acc[j][5] = fmaf(bv[j], q1.y, acc[j][5]);
                acc[j][6] = fmaf(bv[j], q1.z, acc[j][6]);
                acc[j][7] = fmaf(bv[j], q1.w, acc[j][7]);
            }
        }
    };

    // prologue: stage phase 0 synchronously
    {
        const int kp0 = (K < PH) ? K : PH;
        LOADR(0, kp0);
        WRITER(kp0);
        __syncthreads();
    }
    for (int base = 0; base < K; base += PH) {     // K uniform -> no barrier divergence
        const int kpc = (K - base < PH) ? (K - base) : PH;
        const int nb  = base + PH;
        const int kpn = (nb < K) ? ((K - nb < PH) ? (K - nb) : PH) : 0;
        if (kpn) LOADR(nb, kpn);                   // issue next phase early (T14)
        COMPUTE(kpc);                              // pure LDS+FMA: hides vmcnt
        if (kpn) {
            __syncthreads();                       // readers done with current LDS
            WRITER(kpn);                           // vmcnt drains here, then ds_write
            __syncthreads();                       // writes visible
        }
    }

    // ---------- sign-pack (bit j = sbase+sl+j > 0) and store as int32 ----------
    const size_t inl_total = (size_t)NB_HG * DIM_N * 32;   // 8388608
    #pragma unroll
    for (int i = 0; i < 8; ++i) {
        int byte = 0;
        #pragma unroll
        for (int j = 0; j < 8; ++j)
            if (acc[j][i] > 0.0f) byte |= (1 << j);
        const int n = (i < 4) ? (C0 + i) : (64 + C0 + (i - 4));
        size_t idx;
        if (type == 2)
            idx = inl_total + ((size_t)hg * DIM_N + n) * 16 + ts;
        else
            idx = ((size_t)hg * DIM_N + n) * 32 + (type == 1 ? 16 : 0) + ts;
        out[idx] = byte;
    }
}

extern "C" void kernel_launch(void* const* d_in, const int* in_sizes, int n_in,
                              void* d_out, int out_size, void* d_ws, size_t ws_size,
                              hipStream_t stream) {
    const float* data = (const float*)d_in[0];   // (1,32,64,128,128) fp32
    const float* mask = (const float*)d_in[1];   // (1,32,64,128) fp32, values {0,1}
    const float* proj = (const float*)d_in[2];   // (256,128) fp32
    int* out = (int*)d_out;                      // 8388608 inlier + 4194304 outlier int32

    dim3 grid(3, NB_HG);
    const size_t tp_bytes = (size_t)DIM_D * DIM_S * sizeof(float);   // 128 KB
    if (ws_size >= tp_bytes) {
        float* projT = (float*)d_ws;
        transpose_proj_kernel<<<DIM_D, DIM_S, 0, stream>>>(proj, projT);
        qjl_sketch_kernel<true><<<grid, 256, 0, stream>>>(data, mask, projT, out);
    } else {
        qjl_sketch_kernel<false><<<grid, 256, 0, stream>>>(data, mask, proj, out);
    }
}

// Round 14
// 202.975 us; speedup vs baseline: 1.0623x; 1.0623x over previous
//
#include <hip/hip_runtime.h>

#define NB_HG 2048   // H*G = 32*64
#define DIM_N 128
#define DIM_D 128
#define DIM_S 256
#define PH 16        // staged rows per phase (ping-pong: 2 buffers)
#define BSW 128      // staged B width = block's s-window

// Numerics: golden = per-element strictly sequential ascending-d fp32 FMA over
// the SELECTED d's only (masked-out terms exact zeros). Verified bit-exact
// rounds 4-13. Compaction + phase split preserve chain order; X/B pass through
// regs+LDS unmodified (same bits).
// LDS swizzle pos = idx ^ (4*(row&7)) — SQ_LDS_BANK_CONFLICT=0 verified r5-13.
// R13 post-mortem: explicit async-stage spilled (32 in-flight regs + WRITER
// between two barriers = serial drain). This round: PH=16 ping-pong dbuf —
// WRITER hits the OTHER buffer (no pre-barrier), payload 16 regs/thread,
// one barrier per phase, LOADR(p+1) in flight under COMPUTE(p).

__global__ void transpose_proj_kernel(const float* __restrict__ proj,
                                      float* __restrict__ projT)
{
    const int d = blockIdx.x;                      // 128
    const int s = threadIdx.x;                     // 256
    projT[d * DIM_S + s] = proj[s * DIM_D + d];    // coalesced write
}

template<bool TP>
__global__ __launch_bounds__(256)
void qjl_sketch_kernel(const float* __restrict__ data,
                       const float* __restrict__ mask,
                       const float* __restrict__ pmat,   // TP ? projT[d][s] : proj[s][d]
                       int* __restrict__ out)
{
    __shared__ float Xt[2][PH * DIM_N];            // 2 x 8 KB
    __shared__ float Bs[2][PH * BSW];              // 2 x 8 KB
    __shared__ int   cidx[DIM_D];
    __shared__ int   wcnt[2];

    const int type = blockIdx.x;   // 0: inlier s<128, 1: inlier s>=128, 2: outlier s<128
    const int hg   = blockIdx.y;
    const int tid  = threadIdx.x;

    // ---------- build compacted ascending list of selected d's ----------
    bool sel = false; int pos = 0, w = 0;
    if (tid < 128) {                               // waves 0,1 only (whole waves)
        const float m = mask[hg * DIM_D + tid];    // exactly 0.0f or 1.0f
        sel = (type == 2) ? (m != 0.0f) : (m == 0.0f);
        const unsigned long long bal = __ballot(sel);
        const int lane = tid & 63;
        w = tid >> 6;
        if (lane == 0) wcnt[w] = __popcll(bal);
        pos = __popcll(bal & ((1ull << lane) - 1ull));
    }
    __syncthreads();
    if (sel) cidx[pos + (w ? wcnt[0] : 0)] = tid;  // tid == d, ascending preserved
    __syncthreads();
    const int K = wcnt[0] + wcnt[1];               // uniform across block

    const int tn = tid & 15;                       // 16 n-groups
    const int ts = tid >> 4;                       // 16 s-groups
    const int C0 = 4 * tn;
    const int sl = ts * 8;                         // s_local base
    const int sbase = (type == 1) ? 128 : 0;

    float acc[8][8];                               // [j: s-bit][i: n-slot]
    #pragma unroll
    for (int j = 0; j < 8; ++j)
        #pragma unroll
        for (int i = 0; i < 8; ++i) acc[j][i] = 0.0f;

    // staging thread mapping: 16 rows x 16 slices of 8
    const int cl_s  = tid & 15;                    // LDS row this thread stages
    const int nh    = tid >> 4;                    // 0..15: 8-wide slice
    const int pcs_s = 4 * (cl_s & 7);

    float4 xr[2], br[2];                           // in-flight staging regs (16 VGPR)

    auto LOADR = [&](int base, int kp) {
        if (cl_s < kp) {
            const int dg = cidx[base + cl_s];
            const float* Xs = data + (size_t)hg * (DIM_N * DIM_D) + dg;
            #pragma unroll
            for (int g = 0; g < 2; ++g) {
                const int n0 = nh * 8 + g * 4;
                xr[g].x = Xs[(size_t)(n0 + 0) * DIM_D];
                xr[g].y = Xs[(size_t)(n0 + 1) * DIM_D];
                xr[g].z = Xs[(size_t)(n0 + 2) * DIM_D];
                xr[g].w = Xs[(size_t)(n0 + 3) * DIM_D];
            }
            if (TP) {
                const float* Ps = pmat + (size_t)dg * DIM_S + sbase;
                #pragma unroll
                for (int g = 0; g < 2; ++g)
                    br[g] = *reinterpret_cast<const float4*>(Ps + nh * 8 + g * 4);
            } else {
                #pragma unroll
                for (int g = 0; g < 2; ++g) {
                    const int s0l = nh * 8 + g * 4;
                    br[g].x = pmat[(size_t)(sbase + s0l + 0) * DIM_D + dg];
                    br[g].y = pmat[(size_t)(sbase + s0l + 1) * DIM_D + dg];
                    br[g].z = pmat[(size_t)(sbase + s0l + 2) * DIM_D + dg];
                    br[g].w = pmat[(size_t)(sbase + s0l + 3) * DIM_D + dg];
                }
            }
        }
    };
    auto WRITER = [&](int b, int kp) {             // to buffer b (!= compute buffer)
        if (cl_s < kp) {
            float* xrow = &Xt[b][cl_s * DIM_N];
            float* brow = &Bs[b][cl_s * BSW];
            #pragma unroll
            for (int g = 0; g < 2; ++g) {
                const int n0 = nh * 8 + g * 4;
                *reinterpret_cast<float4*>(&xrow[n0 ^ pcs_s]) = xr[g];
                *reinterpret_cast<float4*>(&brow[n0 ^ pcs_s]) = br[g];
            }
        }
    };

    auto COMPUTE = [&](int b, int kp) {
        const float* Xb = Xt[b];
        const float* Bb = Bs[b];
        #pragma unroll 8
        for (int cl = 0; cl < kp; ++cl) {          // ascending selected d
            const int pcs = 4 * (cl & 7);          // compile-time under unroll
            const int pA  = sl ^ pcs;              // holds s_local sl..sl+3
            const float4 bA = *reinterpret_cast<const float4*>(&Bb[cl * BSW + pA]);
            const float4 bB = *reinterpret_cast<const float4*>(&Bb[cl * BSW + (pA ^ 4)]);
            const int P = C0 ^ pcs;
            const float4 q0 = *reinterpret_cast<const float4*>(&Xb[cl * DIM_N + P]);
            const float4 q1 = *reinterpret_cast<const float4*>(&Xb[cl * DIM_N + P + 64]);

            #pragma unroll
            for (int j = 0; j < 8; ++j) {
                const float bv = (j == 0) ? bA.x : (j == 1) ? bA.y : (j == 2) ? bA.z
                               : (j == 3) ? bA.w : (j == 4) ? bB.x : (j == 5) ? bB.y
                               : (j == 6) ? bB.z : bB.w;
                acc[j][0] = fmaf(bv, q0.x, acc[j][0]);   // serial dep: order fixed
                acc[j][1] = fmaf(bv, q0.y, acc[j][1]);
                acc[j][2] = fmaf(bv, q0.z, acc[j][2]);
                acc[j][3] = fmaf(bv, q0.w, acc[j][3]);
                acc[j][4] = fmaf(bv, q1.x, acc[j][4]);
                acc[j][5] = fmaf(bv, q1.y, acc[j][5]);
                acc[j][6] = fmaf(bv, q1.z, acc[j][6]);
                acc[j][7] = fmaf(bv, q1.w, acc[j][7]);
            }
        }
    };

    // prologue: stage phase 0 into buffer 0
    {
        const int kp0 = (K < PH) ? K : PH;
        LOADR(0, kp0);
        WRITER(0, kp0);
        __syncthreads();
    }
    int b = 0;
    for (int base = 0; base < K; base += PH, b ^= 1) {
        const int kpc = (K - base < PH) ? (K - base) : PH;
        const int nb  = base + PH;
        const int kpn = (nb < K) ? ((K - nb < PH) ? (K - nb) : PH) : 0;
        if (kpn) LOADR(nb, kpn);                   // globals in flight under compute
        COMPUTE(b, kpc);                           // pure LDS + FMA (lgkmcnt only)
        if (kpn) {
            WRITER(b ^ 1, kpn);                    // other buffer: no pre-barrier
            __syncthreads();                       // writes visible for next phase
        }
    }

    // ---------- sign-pack (bit j = sbase+sl+j > 0) and store as int32 ----------
    const size_t inl_total = (size_t)NB_HG * DIM_N * 32;   // 8388608
    #pragma unroll
    for (int i = 0; i < 8; ++i) {
        int byte = 0;
        #pragma unroll
        for (int j = 0; j < 8; ++j)
            if (acc[j][i] > 0.0f) byte |= (1 << j);
        const int n = (i < 4) ? (C0 + i) : (64 + C0 + (i - 4));
        size_t idx;
        if (type == 2)
            idx = inl_total + ((size_t)hg * DIM_N + n) * 16 + ts;
        else
            idx = ((size_t)hg * DIM_N + n) * 32 + (type == 1 ? 16 : 0) + ts;
        out[idx] = byte;
    }
}

extern "C" void kernel_launch(void* const* d_in, const int* in_sizes, int n_in,
                              void* d_out, int out_size, void* d_ws, size_t ws_size,
                              hipStream_t stream) {
    const float* data = (const float*)d_in[0];   // (1,32,64,128,128) fp32
    const float* mask = (const float*)d_in[1];   // (1,32,64,128) fp32, values {0,1}
    const float* proj = (const float*)d_in[2];   // (256,128) fp32
    int* out = (int*)d_out;                      // 8388608 inlier + 4194304 outlier int32

    dim3 grid(3, NB_HG);
    const size_t tp_bytes = (size_t)DIM_D * DIM_S * sizeof(float);   // 128 KB
    if (ws_size >= tp_bytes) {
        float* projT = (float*)d_ws;
        transpose_proj_kernel<<<DIM_D, DIM_S, 0, stream>>>(proj, projT);
        qjl_sketch_kernel<true><<<grid, 256, 0, stream>>>(data, mask, projT, out);
    } else {
        qjl_sketch_kernel<false><<<grid, 256, 0, stream>>>(data, mask, proj, out);
    }
}